// Round 1
// baseline (17538.702 us; speedup 1.0000x reference)
//
#include <hip/hip_runtime.h>

#define NTIME   101
#define BATCH   4096
#define DIM     64
#define WIDTH   256
#define TB      16          // batch rows per block
#define NTHREADS 256
#define HPAD    260         // padded LDS row stride for hidden activations (multiple of 4)

// Tsit5 coefficients
#define A21 0.161f
#define A31 (-0.008480655492356989f)
#define A32 0.335480655492357f
#define A41 2.8971530571054935f
#define A42 (-6.359448489975075f)
#define A43 4.3622954328695815f
#define A51 5.325864828439257f
#define A52 (-11.748883564062828f)
#define A53 7.4955393428898365f
#define A54 (-0.09249506636175525f)
#define A61 5.86145544294642f
#define A62 (-12.92096931784711f)
#define A63 8.159367898576159f
#define A64 (-0.071584973281401f)
#define A65 (-0.028269050394068383f)
#define B1 0.09646076681806523f
#define B2 0.01f
#define B3 0.4798896504144996f
#define B4 1.379008574103742f
#define B5 (-3.290069515436081f)
#define B6 2.324710524099774f

__device__ __forceinline__ float fast_tanh(float x) {
    // tanh(x) = 1 - 2/(exp(2x)+1); exact saturation at +/-inf
    float e = __expf(2.0f * x);
    return 1.0f - 2.0f / (e + 1.0f);
}

// out[r][c] = act(b[c] + sum_k in[r][k] * W[k][c]); 16 rows x 256 cols, 256 threads.
// Thread tile: 4 rows x 4 contiguous cols. Activation reads are wave-broadcast LDS
// float4; weight reads are coalesced global float4 (L2-resident).
template<int K>
__device__ __forceinline__ void layer_w256(const float* __restrict__ in, int inStride,
                                           const float* __restrict__ W,
                                           const float* __restrict__ b,
                                           float* __restrict__ out, int outStride,
                                           int tid, bool act)
{
    const int c0 = (tid & 63) << 2;   // 4 contiguous cols, spans 0..255 within a wave
    const int r0 = (tid >> 6) << 2;   // wave id -> 4 contiguous rows (uniform per wave)
    float acc[4][4] = {{0.f,0.f,0.f,0.f},{0.f,0.f,0.f,0.f},
                       {0.f,0.f,0.f,0.f},{0.f,0.f,0.f,0.f}};
    for (int k = 0; k < K; k += 4) {
        float a0[4], a1[4], a2[4], a3[4];
        *(float4*)a0 = *(const float4*)(in + (r0+0)*inStride + k);
        *(float4*)a1 = *(const float4*)(in + (r0+1)*inStride + k);
        *(float4*)a2 = *(const float4*)(in + (r0+2)*inStride + k);
        *(float4*)a3 = *(const float4*)(in + (r0+3)*inStride + k);
        #pragma unroll
        for (int kk = 0; kk < 4; ++kk) {
            float w[4];
            *(float4*)w = *(const float4*)(W + (k+kk)*256 + c0);
            #pragma unroll
            for (int c = 0; c < 4; ++c) {
                acc[0][c] = fmaf(a0[kk], w[c], acc[0][c]);
                acc[1][c] = fmaf(a1[kk], w[c], acc[1][c]);
                acc[2][c] = fmaf(a2[kk], w[c], acc[2][c]);
                acc[3][c] = fmaf(a3[kk], w[c], acc[3][c]);
            }
        }
    }
    float bb[4];
    *(float4*)bb = *(const float4*)(b + c0);
    #pragma unroll
    for (int r = 0; r < 4; ++r) {
        float o[4];
        #pragma unroll
        for (int c = 0; c < 4; ++c) {
            float v = acc[r][c] + bb[c];
            o[c] = act ? fast_tanh(v) : v;
        }
        *(float4*)(out + (r0+r)*outStride + c0) = *(float4*)o;
    }
}

// Final layer: 16 rows x 64 cols from 16x256 input. Thread tile: 1 row x 4 cols.
__device__ __forceinline__ void layer_w64(const float* __restrict__ in, int inStride,
                                          const float* __restrict__ W,
                                          const float* __restrict__ b,
                                          float* __restrict__ out, int tid)
{
    const int c0 = (tid & 15) << 2;
    const int r  = tid >> 4;
    float acc[4] = {0.f, 0.f, 0.f, 0.f};
    for (int k = 0; k < 256; k += 4) {
        float a[4];
        *(float4*)a = *(const float4*)(in + r*inStride + k);
        #pragma unroll
        for (int kk = 0; kk < 4; ++kk) {
            float w[4];
            *(float4*)w = *(const float4*)(W + (k+kk)*64 + c0);
            #pragma unroll
            for (int c = 0; c < 4; ++c) acc[c] = fmaf(a[kk], w[c], acc[c]);
        }
    }
    float bb[4];
    *(float4*)bb = *(const float4*)(b + c0);
    float o[4];
    #pragma unroll
    for (int c = 0; c < 4; ++c) o[c] = acc[c] + bb[c];
    *(float4*)(out + r*64 + c0) = *(float4*)o;
}

__device__ __forceinline__ void feval(const float* in,   // [16][64], stride 64, LDS
                                      float* kout,       // [16][64] LDS
                                      const float* __restrict__ W0, const float* __restrict__ b0,
                                      const float* __restrict__ W1, const float* __restrict__ b1,
                                      const float* __restrict__ W2, const float* __restrict__ b2,
                                      const float* __restrict__ W3, const float* __restrict__ b3,
                                      float* sHA, float* sHB, int tid)
{
    layer_w256<DIM>(in, DIM, W0, b0, sHA, HPAD, tid, true);
    __syncthreads();
    layer_w256<WIDTH>(sHA, HPAD, W1, b1, sHB, HPAD, tid, true);
    __syncthreads();
    layer_w256<WIDTH>(sHB, HPAD, W2, b2, sHA, HPAD, tid, true);
    __syncthreads();
    layer_w64(sHA, HPAD, W3, b3, kout, tid);
    __syncthreads();
}

__global__ void __launch_bounds__(NTHREADS)
ode_kernel(const float* __restrict__ ts, const float* __restrict__ y0,
           const float* __restrict__ W0, const float* __restrict__ b0,
           const float* __restrict__ W1, const float* __restrict__ b1,
           const float* __restrict__ W2, const float* __restrict__ b2,
           const float* __restrict__ W3, const float* __restrict__ b3,
           float* __restrict__ out)
{
    __shared__ __align__(16) float sY[TB*DIM];
    __shared__ __align__(16) float sK[6][TB*DIM];
    __shared__ __align__(16) float sHA[TB*HPAD];
    __shared__ __align__(16) float sHB[TB*HPAD];
    float* sT = sHB;  // stage-input aliases sHB: fully consumed by layer0 before L1 writes sHB

    const int tid = threadIdx.x;
    const long base = (long)blockIdx.x * (TB*DIM);

    // Load y0 slice; emit step 0
    for (int i = tid; i < TB*DIM; i += NTHREADS) {
        float v = y0[base + i];
        sY[i] = v;
        out[base + i] = v;
    }
    __syncthreads();

    for (int t = 0; t < NTIME-1; ++t) {
        const float h = ts[t+1] - ts[t];

        // stage 1: k1 = f(y)
        feval(sY, sK[0], W0,b0,W1,b1,W2,b2,W3,b3, sHA, sHB, tid);

        // stage 2
        for (int i = tid; i < TB*DIM; i += NTHREADS)
            sT[i] = fmaf(h, A21*sK[0][i], sY[i]);
        __syncthreads();
        feval(sT, sK[1], W0,b0,W1,b1,W2,b2,W3,b3, sHA, sHB, tid);

        // stage 3
        for (int i = tid; i < TB*DIM; i += NTHREADS)
            sT[i] = fmaf(h, fmaf(A31, sK[0][i], A32*sK[1][i]), sY[i]);
        __syncthreads();
        feval(sT, sK[2], W0,b0,W1,b1,W2,b2,W3,b3, sHA, sHB, tid);

        // stage 4
        for (int i = tid; i < TB*DIM; i += NTHREADS) {
            float s = A41*sK[0][i] + A42*sK[1][i] + A43*sK[2][i];
            sT[i] = fmaf(h, s, sY[i]);
        }
        __syncthreads();
        feval(sT, sK[3], W0,b0,W1,b1,W2,b2,W3,b3, sHA, sHB, tid);

        // stage 5
        for (int i = tid; i < TB*DIM; i += NTHREADS) {
            float s = A51*sK[0][i] + A52*sK[1][i] + A53*sK[2][i] + A54*sK[3][i];
            sT[i] = fmaf(h, s, sY[i]);
        }
        __syncthreads();
        feval(sT, sK[4], W0,b0,W1,b1,W2,b2,W3,b3, sHA, sHB, tid);

        // stage 6
        for (int i = tid; i < TB*DIM; i += NTHREADS) {
            float s = A61*sK[0][i] + A62*sK[1][i] + A63*sK[2][i] + A64*sK[3][i] + A65*sK[4][i];
            sT[i] = fmaf(h, s, sY[i]);
        }
        __syncthreads();
        feval(sT, sK[5], W0,b0,W1,b1,W2,b2,W3,b3, sHA, sHB, tid);

        // final combination + output
        for (int i = tid; i < TB*DIM; i += NTHREADS) {
            float s = B1*sK[0][i] + B2*sK[1][i] + B3*sK[2][i]
                    + B4*sK[3][i] + B5*sK[4][i] + B6*sK[5][i];
            float v = fmaf(h, s, sY[i]);
            sY[i] = v;
            out[(long)(t+1)*(BATCH*DIM) + base + i] = v;
        }
        __syncthreads();
    }
}

extern "C" void kernel_launch(void* const* d_in, const int* in_sizes, int n_in,
                              void* d_out, int out_size, void* d_ws, size_t ws_size,
                              hipStream_t stream) {
    (void)in_sizes; (void)n_in; (void)ws_size; (void)d_ws; (void)out_size;
    const float* ts = (const float*)d_in[0];
    const float* y0 = (const float*)d_in[1];
    const float* W0 = (const float*)d_in[2];
    const float* b0 = (const float*)d_in[3];
    const float* W1 = (const float*)d_in[4];
    const float* b1 = (const float*)d_in[5];
    const float* W2 = (const float*)d_in[6];
    const float* b2 = (const float*)d_in[7];
    const float* W3 = (const float*)d_in[8];
    const float* b3 = (const float*)d_in[9];
    float* out = (float*)d_out;
    hipLaunchKernelGGL(ode_kernel, dim3(BATCH/TB), dim3(NTHREADS), 0, stream,
                       ts, y0, W0, b0, W1, b1, W2, b2, W3, b3, out);
}

// Round 2
// 9016.149 us; speedup vs baseline: 1.9453x; 1.9453x over previous
//
#include <hip/hip_runtime.h>

#define NTIME   101
#define BATCH   4096
#define DIM     64
#define WIDTH   256
#define TB      16
#define NTHREADS 256
#define HPAD    260   // hidden LDS row stride (floats): 260%32=4 -> 2-way bank alias (free), 16B aligned
#define YSTR    68    // y/stage-input LDS row stride: 68%32=4 -> 2-way, 16B aligned

// Tsit5 coefficients
#define A21 0.161f
#define A31 (-0.008480655492356989f)
#define A32 0.335480655492357f
#define A41 2.8971530571054935f
#define A42 (-6.359448489975075f)
#define A43 4.3622954328695815f
#define A51 5.325864828439257f
#define A52 (-11.748883564062828f)
#define A53 7.4955393428898365f
#define A54 (-0.09249506636175525f)
#define A61 5.86145544294642f
#define A62 (-12.92096931784711f)
#define A63 8.159367898576159f
#define A64 (-0.071584973281401f)
#define A65 (-0.028269050394068383f)
#define B1 0.09646076681806523f
#define B2 0.01f
#define B3 0.4798896504144996f
#define B4 1.379008574103742f
#define B5 (-3.290069515436081f)
#define B6 2.324710524099774f

typedef float  floatx4 __attribute__((ext_vector_type(4)));
typedef _Float16 halfx8 __attribute__((ext_vector_type(8)));

// packed-weight segment offsets in d_ws (in _Float16 elements)
#define L0S1 0
#define L0S2 16384
#define L1S1 32768
#define L1S2 98304
#define L2S1 163840
#define L2S2 229376
#define L3S1 294912
#define L3S2 311296
// total 327680 halves = 655360 bytes

__device__ __forceinline__ float fast_tanh(float x) {
    float e = __expf(2.0f * x);
    return 1.0f - 2.0f / (e + 1.0f);
}

// Prologue: split fp32 weights into scaled fp16 pairs and pack into MFMA
// B-fragment layout. Fragment block fb = nt*(K/32)+kc is 64 lanes x 8 halves;
// lane = q*16 + (n&15) supplies B[k = kc*32 + q*8 + j][n].
__global__ void pack_weights(const float* __restrict__ W0, const float* __restrict__ W1,
                             const float* __restrict__ W2, const float* __restrict__ W3,
                             _Float16* __restrict__ ws)
{
    int idx = blockIdx.x * 256 + threadIdx.x;
    const float* W; int K, N, e; size_t d1, d2;
    if (idx < 16384)       { W = W0; K = 64;  N = 256; e = idx;          d1 = L0S1; d2 = L0S2; }
    else if (idx < 81920)  { W = W1; K = 256; N = 256; e = idx - 16384;  d1 = L1S1; d2 = L1S2; }
    else if (idx < 147456) { W = W2; K = 256; N = 256; e = idx - 81920;  d1 = L2S1; d2 = L2S2; }
    else if (idx < 163840) { W = W3; K = 256; N = 64;  e = idx - 147456; d1 = L3S1; d2 = L3S2; }
    else return;
    int k = e / N, n = e % N;
    float w = W[e];
    _Float16 h1 = (_Float16)w;                                // RNE
    _Float16 h2 = (_Float16)((w - (float)h1) * 4096.0f);      // scaled residual (avoids fp16 subnormals)
    int kc = k >> 5, q = (k >> 3) & 3, j = k & 7, nt = n >> 4, nc = n & 15;
    size_t off = ((size_t)((nt * (K / 32) + kc) * 64 + q * 16 + nc)) * 8 + j;
    ws[d1 + off] = h1;
    ws[d2 + off] = h2;
}

// One dense layer on a 16-row batch tile via fp16 2-split MFMA emulation.
// in: LDS fp32 [16][inStride]; out: LDS fp32 [16][outStride].
// Each wave computes NT n-tiles of 16 cols (wave w -> tiles w*NT .. w*NT+NT-1).
template<int K, int NT>
__device__ __forceinline__ void layer_mfma(const float* __restrict__ in, int inStride,
                                           const _Float16* __restrict__ B1g,
                                           const _Float16* __restrict__ B2g,
                                           const float* __restrict__ bias,
                                           float* __restrict__ out, int outStride,
                                           bool act, int tid)
{
    constexpr int KC = K / 32;
    const int lane = tid & 63;
    const int wave = tid >> 6;
    const int m = lane & 15;     // A-operand row / C-operand col
    const int q = lane >> 4;     // k-quad / C-row group

    floatx4 acc1[NT], acc2[NT];
    #pragma unroll
    for (int nt = 0; nt < NT; ++nt) { acc1[nt] = (floatx4)0.0f; acc2[nt] = (floatx4)0.0f; }

    float  av[2][8];
    halfx8 vb1[2][NT], vb2[2][NT];

    // prefetch kc = 0
    {
        const float* ap = in + m * inStride + q * 8;
        *(float4*)&av[0][0] = *(const float4*)ap;
        *(float4*)&av[0][4] = *(const float4*)(ap + 4);
        #pragma unroll
        for (int nt = 0; nt < NT; ++nt) {
            const int fb = ((wave * NT + nt) * KC) * 64 + lane;
            vb1[0][nt] = *(const halfx8*)(B1g + (size_t)fb * 8);
            vb2[0][nt] = *(const halfx8*)(B2g + (size_t)fb * 8);
        }
    }

    #pragma unroll
    for (int kc = 0; kc < KC; ++kc) {
        const int cur = kc & 1, nxt = cur ^ 1;
        if (kc + 1 < KC) {  // software-pipeline next chunk (hides L2 latency)
            const float* ap = in + m * inStride + (kc + 1) * 32 + q * 8;
            *(float4*)&av[nxt][0] = *(const float4*)ap;
            *(float4*)&av[nxt][4] = *(const float4*)(ap + 4);
            #pragma unroll
            for (int nt = 0; nt < NT; ++nt) {
                const int fb = ((wave * NT + nt) * KC + (kc + 1)) * 64 + lane;
                vb1[nxt][nt] = *(const halfx8*)(B1g + (size_t)fb * 8);
                vb2[nxt][nt] = *(const halfx8*)(B2g + (size_t)fb * 8);
            }
        }
        halfx8 a1, a2;
        #pragma unroll
        for (int j = 0; j < 8; ++j) {
            float f = av[cur][j];
            _Float16 h = (_Float16)f;
            a1[j] = h;
            a2[j] = (_Float16)((f - (float)h) * 4096.0f);
        }
        #pragma unroll
        for (int nt = 0; nt < NT; ++nt)
            acc1[nt] = __builtin_amdgcn_mfma_f32_16x16x32_f16(a1, vb1[cur][nt], acc1[nt], 0, 0, 0);
        #pragma unroll
        for (int nt = 0; nt < NT; ++nt)
            acc2[nt] = __builtin_amdgcn_mfma_f32_16x16x32_f16(a1, vb2[cur][nt], acc2[nt], 0, 0, 0);
        #pragma unroll
        for (int nt = 0; nt < NT; ++nt)
            acc2[nt] = __builtin_amdgcn_mfma_f32_16x16x32_f16(a2, vb1[cur][nt], acc2[nt], 0, 0, 0);
    }

    #pragma unroll
    for (int nt = 0; nt < NT; ++nt) {
        const int col = (wave * NT + nt) * 16 + m;
        const float bb = bias[col];
        #pragma unroll
        for (int v = 0; v < 4; ++v) {
            const int row = q * 4 + v;   // m89-verified C/D mapping
            float val = acc1[nt][v] + acc2[nt][v] * (1.0f / 4096.0f) + bb;
            if (act) val = fast_tanh(val);
            out[row * outStride + col] = val;
        }
    }
}

__device__ __forceinline__ void feval(const float* in /*[16][YSTR]*/, float* kout /*[16][64]*/,
                                      const _Float16* ws, const float* sBias,
                                      float* sHA, float* sHB, int tid)
{
    layer_mfma<64, 4>(in, YSTR, ws + L0S1, ws + L0S2, sBias + 0, sHA, HPAD, true, tid);
    __syncthreads();
    layer_mfma<256, 4>(sHA, HPAD, ws + L1S1, ws + L1S2, sBias + 256, sHB, HPAD, true, tid);
    __syncthreads();
    layer_mfma<256, 4>(sHB, HPAD, ws + L2S1, ws + L2S2, sBias + 512, sHA, HPAD, true, tid);
    __syncthreads();
    layer_mfma<256, 1>(sHA, HPAD, ws + L3S1, ws + L3S2, sBias + 768, kout, 64, false, tid);
    __syncthreads();
}

__global__ void __launch_bounds__(NTHREADS)
ode_kernel(const float* __restrict__ ts, const float* __restrict__ y0,
           const float* __restrict__ b0, const float* __restrict__ b1,
           const float* __restrict__ b2, const float* __restrict__ b3,
           const _Float16* __restrict__ ws, float* __restrict__ out)
{
    __shared__ __align__(16) float sY[TB * YSTR];
    __shared__ __align__(16) float sT[TB * YSTR];
    __shared__ __align__(16) float sK[6][TB * DIM];
    __shared__ __align__(16) float sHA[TB * HPAD];
    __shared__ __align__(16) float sHB[TB * HPAD];
    __shared__ __align__(16) float sBias[832];

    const int tid = threadIdx.x;
    const long base = (long)blockIdx.x * (TB * DIM);

    for (int i = tid; i < 832; i += NTHREADS) {
        float v;
        if (i < 256)      v = b0[i];
        else if (i < 512) v = b1[i - 256];
        else if (i < 768) v = b2[i - 512];
        else              v = b3[i - 768];
        sBias[i] = v;
    }
    for (int i = tid; i < TB * DIM; i += NTHREADS) {
        int r = i >> 6, c = i & 63;
        float v = y0[base + i];
        sY[r * YSTR + c] = v;
        out[base + i] = v;
    }
    __syncthreads();

    for (int t = 0; t < NTIME - 1; ++t) {
        const float h = ts[t + 1] - ts[t];

        feval(sY, sK[0], ws, sBias, sHA, sHB, tid);

        for (int i = tid; i < TB * DIM; i += NTHREADS) {
            int r = i >> 6, c = i & 63;
            sT[r * YSTR + c] = fmaf(h, A21 * sK[0][i], sY[r * YSTR + c]);
        }
        __syncthreads();
        feval(sT, sK[1], ws, sBias, sHA, sHB, tid);

        for (int i = tid; i < TB * DIM; i += NTHREADS) {
            int r = i >> 6, c = i & 63;
            sT[r * YSTR + c] = fmaf(h, fmaf(A31, sK[0][i], A32 * sK[1][i]), sY[r * YSTR + c]);
        }
        __syncthreads();
        feval(sT, sK[2], ws, sBias, sHA, sHB, tid);

        for (int i = tid; i < TB * DIM; i += NTHREADS) {
            int r = i >> 6, c = i & 63;
            float s = A41 * sK[0][i] + A42 * sK[1][i] + A43 * sK[2][i];
            sT[r * YSTR + c] = fmaf(h, s, sY[r * YSTR + c]);
        }
        __syncthreads();
        feval(sT, sK[3], ws, sBias, sHA, sHB, tid);

        for (int i = tid; i < TB * DIM; i += NTHREADS) {
            int r = i >> 6, c = i & 63;
            float s = A51 * sK[0][i] + A52 * sK[1][i] + A53 * sK[2][i] + A54 * sK[3][i];
            sT[r * YSTR + c] = fmaf(h, s, sY[r * YSTR + c]);
        }
        __syncthreads();
        feval(sT, sK[4], ws, sBias, sHA, sHB, tid);

        for (int i = tid; i < TB * DIM; i += NTHREADS) {
            int r = i >> 6, c = i & 63;
            float s = A61 * sK[0][i] + A62 * sK[1][i] + A63 * sK[2][i] + A64 * sK[3][i] + A65 * sK[4][i];
            sT[r * YSTR + c] = fmaf(h, s, sY[r * YSTR + c]);
        }
        __syncthreads();
        feval(sT, sK[5], ws, sBias, sHA, sHB, tid);

        for (int i = tid; i < TB * DIM; i += NTHREADS) {
            int r = i >> 6, c = i & 63;
            float s = B1 * sK[0][i] + B2 * sK[1][i] + B3 * sK[2][i]
                    + B4 * sK[3][i] + B5 * sK[4][i] + B6 * sK[5][i];
            float v = fmaf(h, s, sY[r * YSTR + c]);
            sY[r * YSTR + c] = v;
            out[(long)(t + 1) * (BATCH * DIM) + base + i] = v;
        }
        __syncthreads();
    }
}

extern "C" void kernel_launch(void* const* d_in, const int* in_sizes, int n_in,
                              void* d_out, int out_size, void* d_ws, size_t ws_size,
                              hipStream_t stream) {
    (void)in_sizes; (void)n_in; (void)ws_size; (void)out_size;
    const float* ts = (const float*)d_in[0];
    const float* y0 = (const float*)d_in[1];
    const float* W0 = (const float*)d_in[2];
    const float* b0 = (const float*)d_in[3];
    const float* W1 = (const float*)d_in[4];
    const float* b1 = (const float*)d_in[5];
    const float* W2 = (const float*)d_in[6];
    const float* b2 = (const float*)d_in[7];
    const float* W3 = (const float*)d_in[8];
    const float* b3 = (const float*)d_in[9];
    _Float16* ws = (_Float16*)d_ws;
    float* out = (float*)d_out;

    hipLaunchKernelGGL(pack_weights, dim3(640), dim3(256), 0, stream, W0, W1, W2, W3, ws);
    hipLaunchKernelGGL(ode_kernel, dim3(BATCH / TB), dim3(NTHREADS), 0, stream,
                       ts, y0, b0, b1, b2, b3, ws, out);
}

// Round 3
// 6835.923 us; speedup vs baseline: 2.5657x; 1.3189x over previous
//
#include <hip/hip_runtime.h>

#define NTIME   101
#define BATCH   4096
#define DIM     64
#define WIDTH   256
#define TB      16
#define NTHREADS 1024
#define AST     264   // A-split LDS row stride in halves: 528 B, 16B-aligned, 2-way bank alias (free)

// Tsit5 coefficients
#define A21 0.161f
#define A31 (-0.008480655492356989f)
#define A32 0.335480655492357f
#define A41 2.8971530571054935f
#define A42 (-6.359448489975075f)
#define A43 4.3622954328695815f
#define A51 5.325864828439257f
#define A52 (-11.748883564062828f)
#define A53 7.4955393428898365f
#define A54 (-0.09249506636175525f)
#define A61 5.86145544294642f
#define A62 (-12.92096931784711f)
#define A63 8.159367898576159f
#define A64 (-0.071584973281401f)
#define A65 (-0.028269050394068383f)
#define B1 0.09646076681806523f
#define B2 0.01f
#define B3 0.4798896504144996f
#define B4 1.379008574103742f
#define B5 (-3.290069515436081f)
#define B6 2.324710524099774f

typedef float  floatx4 __attribute__((ext_vector_type(4)));
typedef _Float16 halfx8 __attribute__((ext_vector_type(8)));

// packed-weight segment offsets in d_ws (in _Float16 elements)
#define L0S1 0
#define L0S2 16384
#define L1S1 32768
#define L1S2 98304
#define L2S1 163840
#define L2S2 229376
#define L3S1 294912
#define L3S2 311296

__device__ __forceinline__ float fast_tanh(float x) {
    float e = __expf(2.0f * x);
    return 1.0f - 2.0f / (e + 1.0f);
}

// Split fp32 weights into scaled fp16 pairs, pack into MFMA B-fragment layout.
// Fragment block fb = nt*(K/32)+kc: 64 lanes x 8 halves; lane = q*16 + (n&15)
// supplies B[k = kc*32 + q*8 + j][n].
__global__ void pack_weights(const float* __restrict__ W0, const float* __restrict__ W1,
                             const float* __restrict__ W2, const float* __restrict__ W3,
                             _Float16* __restrict__ ws)
{
    int idx = blockIdx.x * 256 + threadIdx.x;
    const float* W; int K, N, e; size_t d1, d2;
    if (idx < 16384)       { W = W0; K = 64;  N = 256; e = idx;          d1 = L0S1; d2 = L0S2; }
    else if (idx < 81920)  { W = W1; K = 256; N = 256; e = idx - 16384;  d1 = L1S1; d2 = L1S2; }
    else if (idx < 147456) { W = W2; K = 256; N = 256; e = idx - 81920;  d1 = L2S1; d2 = L2S2; }
    else if (idx < 163840) { W = W3; K = 256; N = 64;  e = idx - 147456; d1 = L3S1; d2 = L3S2; }
    else return;
    int k = e / N, n = e % N;
    float w = W[e];
    _Float16 h1 = (_Float16)w;
    _Float16 h2 = (_Float16)((w - (float)h1) * 4096.0f);
    int kc = k >> 5, q = (k >> 3) & 3, j = k & 7, nt = n >> 4, nc = n & 15;
    size_t off = ((size_t)((nt * (K / 32) + kc) * 64 + q * 16 + nc)) * 8 + j;
    ws[d1 + off] = h1;
    ws[d2 + off] = h2;
}

// K-loop for one 16x16 output tile: KCNT chunks of K=32, fp16 2-split emulation.
// A splits come from LDS (ds_read_b128), B fragments from global (L2-resident),
// both software-pipelined one chunk ahead.
template<int KCNT>
__device__ __forceinline__ void mfma_run(const _Float16* __restrict__ pA1,
                                         const _Float16* __restrict__ pA2,
                                         const _Float16* __restrict__ B1g,
                                         const _Float16* __restrict__ B2g,
                                         int fbBase, int kcStart, int lane,
                                         floatx4& acc1o, floatx4& acc2o)
{
    const int m = lane & 15, q = lane >> 4;
    floatx4 acc1 = (floatx4)0.0f, acc2 = (floatx4)0.0f;
    halfx8 va1[2], va2[2], vb1[2], vb2[2];

    const int aOff0 = m * AST + kcStart * 32 + q * 8;
    const size_t fOff0 = ((size_t)fbBase * 64 + lane) * 8;
    vb1[0] = *(const halfx8*)(B1g + fOff0);
    vb2[0] = *(const halfx8*)(B2g + fOff0);
    va1[0] = *(const halfx8*)(pA1 + aOff0);
    va2[0] = *(const halfx8*)(pA2 + aOff0);

    #pragma unroll
    for (int i = 0; i < KCNT; ++i) {
        const int cur = i & 1, nxt = cur ^ 1;
        if (i + 1 < KCNT) {
            const size_t fOff = ((size_t)(fbBase + i + 1) * 64 + lane) * 8;
            vb1[nxt] = *(const halfx8*)(B1g + fOff);
            vb2[nxt] = *(const halfx8*)(B2g + fOff);
            const int aOff = m * AST + (kcStart + i + 1) * 32 + q * 8;
            va1[nxt] = *(const halfx8*)(pA1 + aOff);
            va2[nxt] = *(const halfx8*)(pA2 + aOff);
        }
        acc1 = __builtin_amdgcn_mfma_f32_16x16x32_f16(va1[cur], vb1[cur], acc1, 0, 0, 0);
        acc2 = __builtin_amdgcn_mfma_f32_16x16x32_f16(va1[cur], vb2[cur], acc2, 0, 0, 0);
        acc2 = __builtin_amdgcn_mfma_f32_16x16x32_f16(va2[cur], vb1[cur], acc2, 0, 0, 0);
    }
    acc1o = acc1; acc2o = acc2;
}

// Hidden-layer epilogue: combine splits, bias, tanh, write fp16 split planes.
__device__ __forceinline__ void hidden_epi(floatx4 a1, floatx4 a2,
                                           const float* __restrict__ bias,
                                           _Float16* __restrict__ o1,
                                           _Float16* __restrict__ o2,
                                           int w, int lane)
{
    const int m = lane & 15, q = lane >> 4;
    const int col = (w << 4) + m;
    const float bb = bias[col];
    #pragma unroll
    for (int v = 0; v < 4; ++v) {
        float val = fast_tanh(a1[v] + a2[v] * (1.0f / 4096.0f) + bb);
        _Float16 h1 = (_Float16)val;
        _Float16 h2 = (_Float16)((val - (float)h1) * 4096.0f);
        const int idx = (q * 4 + v) * AST + col;   // m89-verified C/D mapping
        o1[idx] = h1;
        o2[idx] = h2;
    }
}

__global__ void __launch_bounds__(NTHREADS)
ode_kernel(const float* __restrict__ ts, const float* __restrict__ y0,
           const float* __restrict__ b0, const float* __restrict__ b1,
           const float* __restrict__ b2, const float* __restrict__ b3,
           const _Float16* __restrict__ ws, float* __restrict__ out)
{
    // parity-0 / parity-1 A-split buffers
    __shared__ __align__(16) _Float16 sA1[2][TB * AST];
    __shared__ __align__(16) _Float16 sA2[2][TB * AST];
    __shared__ __align__(16) float sK[5][TB * DIM];
    __shared__ __align__(16) float sY[TB * DIM];
    __shared__ __align__(16) float sP[4 * TB * DIM];
    __shared__ __align__(16) float sBias[832];

    const int tid  = threadIdx.x;
    const int lane = tid & 63;
    const int w    = tid >> 6;
    const long base = (long)blockIdx.x * (TB * DIM);
    const int c = tid & 63;       // element column (feature)
    const int r = tid >> 6;       // element row (batch row within tile)

    if (tid < 832) {
        float v;
        if (tid < 256)      v = b0[tid];
        else if (tid < 512) v = b1[tid - 256];
        else if (tid < 768) v = b2[tid - 512];
        else                v = b3[tid - 768];
        sBias[tid] = v;
    }
    {
        float v = y0[base + tid];
        sY[tid] = v;
        out[base + tid] = v;
        _Float16 h1 = (_Float16)v;
        _Float16 h2 = (_Float16)((v - (float)h1) * 4096.0f);
        sA1[0][r * AST + c] = h1;
        sA2[0][r * AST + c] = h2;
    }
    __syncthreads();

    for (int t = 0; t < NTIME - 1; ++t) {
        const float h = ts[t + 1] - ts[t];

        #pragma unroll 1
        for (int s = 0; s < 6; ++s) {
            floatx4 a1, a2;
            // L0: reads parity 0 (cols 0..63), writes parity 1
            mfma_run<2>(sA1[0], sA2[0], ws + L0S1, ws + L0S2, w * 2, 0, lane, a1, a2);
            hidden_epi(a1, a2, sBias + 0, sA1[1], sA2[1], w, lane);
            __syncthreads();
            // L1: parity 1 -> parity 0
            mfma_run<8>(sA1[1], sA2[1], ws + L1S1, ws + L1S2, w * 8, 0, lane, a1, a2);
            hidden_epi(a1, a2, sBias + 256, sA1[0], sA2[0], w, lane);
            __syncthreads();
            // L2: parity 0 -> parity 1
            mfma_run<8>(sA1[0], sA2[0], ws + L2S1, ws + L2S2, w * 8, 0, lane, a1, a2);
            hidden_epi(a1, a2, sBias + 512, sA1[1], sA2[1], w, lane);
            __syncthreads();
            // L3: parity 1 -> partials in sP (4-way K-split across wave groups)
            {
                const int nt = w & 3, kg = w >> 2;
                mfma_run<2>(sA1[1], sA2[1], ws + L3S1, ws + L3S2,
                            nt * 8 + kg * 2, kg * 2, lane, a1, a2);
                const int m = lane & 15, q = lane >> 4;
                #pragma unroll
                for (int v = 0; v < 4; ++v)
                    sP[kg * (TB * DIM) + (q * 4 + v) * 64 + nt * 16 + m]
                        = a1[v] + a2[v] * (1.0f / 4096.0f);
            }
            __syncthreads();

            // element-wise: reduce partials -> k_s, form next stage input (or y update)
            float kv = sP[tid] + sP[1024 + tid] + sP[2048 + tid] + sP[3072 + tid]
                     + sBias[768 + c];
            float v;
            if (s == 0) {
                sK[0][tid] = kv;
                v = fmaf(h, A21 * kv, sY[tid]);
            } else if (s == 1) {
                sK[1][tid] = kv;
                v = fmaf(h, fmaf(A31, sK[0][tid], A32 * kv), sY[tid]);
            } else if (s == 2) {
                sK[2][tid] = kv;
                float sum = A41 * sK[0][tid] + A42 * sK[1][tid] + A43 * kv;
                v = fmaf(h, sum, sY[tid]);
            } else if (s == 3) {
                sK[3][tid] = kv;
                float sum = A51 * sK[0][tid] + A52 * sK[1][tid] + A53 * sK[2][tid] + A54 * kv;
                v = fmaf(h, sum, sY[tid]);
            } else if (s == 4) {
                sK[4][tid] = kv;
                float sum = A61 * sK[0][tid] + A62 * sK[1][tid] + A63 * sK[2][tid]
                          + A64 * sK[3][tid] + A65 * kv;
                v = fmaf(h, sum, sY[tid]);
            } else {
                float sum = B1 * sK[0][tid] + B2 * sK[1][tid] + B3 * sK[2][tid]
                          + B4 * sK[3][tid] + B5 * sK[4][tid] + B6 * kv;
                v = fmaf(h, sum, sY[tid]);
                sY[tid] = v;
                out[(long)(t + 1) * (BATCH * DIM) + base + tid] = v;
            }
            _Float16 h1 = (_Float16)v;
            _Float16 h2 = (_Float16)((v - (float)h1) * 4096.0f);
            sA1[0][r * AST + c] = h1;
            sA2[0][r * AST + c] = h2;
            __syncthreads();
        }
    }
}

extern "C" void kernel_launch(void* const* d_in, const int* in_sizes, int n_in,
                              void* d_out, int out_size, void* d_ws, size_t ws_size,
                              hipStream_t stream) {
    (void)in_sizes; (void)n_in; (void)ws_size; (void)out_size;
    const float* ts = (const float*)d_in[0];
    const float* y0 = (const float*)d_in[1];
    const float* W0 = (const float*)d_in[2];
    const float* b0 = (const float*)d_in[3];
    const float* W1 = (const float*)d_in[4];
    const float* b1 = (const float*)d_in[5];
    const float* W2 = (const float*)d_in[6];
    const float* b2 = (const float*)d_in[7];
    const float* W3 = (const float*)d_in[8];
    const float* b3 = (const float*)d_in[9];
    _Float16* ws = (_Float16*)d_ws;
    float* out = (float*)d_out;

    hipLaunchKernelGGL(pack_weights, dim3(640), dim3(256), 0, stream, W0, W1, W2, W3, ws);
    hipLaunchKernelGGL(ode_kernel, dim3(BATCH / TB), dim3(NTHREADS), 0, stream,
                       ts, y0, b0, b1, b2, b3, ws, out);
}